// Round 4
// baseline (832.730 us; speedup 1.0000x reference)
//
#include <hip/hip_runtime.h>
#include <math.h>

// Problem constants (fixed by reference)
#define B_    16
#define NP_   1024
#define FEAT_ 512
#define H_    1024
#define E_    262144          // B*NP*DEG
#define EPG_  16384           // edges per graph (edge list is graph-sorted)
#define K1_   820             // ceil(0.8*1024)
#define K2_   656             // ceil(0.8*820)
#define K3_   525             // ceil(0.8*656)
#define M1_   16384           // B*NP
#define M2_   13120           // B*K1
#define M3_   10496           // B*K2
// padded row counts: multiples of 256 (256-row GEMM panels), panel*4 divisible by 8
#define MP1_  16384           // 64 panels
#define MP2_  13312           // 52 panels
#define MP3_  11264           // 44 panels
#define SPROWS_ 16384         // scoresPart row stride

typedef unsigned short ushort_t;
typedef __bf16 bf16x8 __attribute__((ext_vector_type(8)));
typedef float f32x4 __attribute__((ext_vector_type(4)));

// ---- bf16 split helpers (RNE) ----
__device__ inline ushort_t f2bf(float f) {
    unsigned u = __float_as_uint(f);
    u += 0x7FFF + ((u >> 16) & 1);
    return (ushort_t)(u >> 16);
}
__device__ inline float bf2f(ushort_t h) {
    return __uint_as_float(((unsigned)h) << 16);
}
__device__ inline void split1(float v, ushort_t& hi, ushort_t& lo) {
    hi = f2bf(v);
    lo = f2bf(v - bf2f(hi));
}

__device__ inline void gll16(const void* g, void* l) {
    __builtin_amdgcn_global_load_lds((__attribute__((address_space(1))) void*)g,
                                     (__attribute__((address_space(3))) void*)l, 16, 0, 0);
}

// ---------------- prep2: csr0 (blocks 0-15) + pnorms (16-18) + weight pack (19+) ----------------

__global__ __launch_bounds__(1024) void prep2_kernel(const int* __restrict__ ei,
                                                     int* __restrict__ counts,
                                                     int* __restrict__ offsets,
                                                     int* __restrict__ adj,
                                                     const float* __restrict__ p1,
                                                     const float* __restrict__ p2,
                                                     const float* __restrict__ p3,
                                                     float* __restrict__ pnout,
                                                     const float* __restrict__ W1l, const float* __restrict__ W1r,
                                                     const float* __restrict__ W2l, const float* __restrict__ W2r,
                                                     const float* __restrict__ W3l, const float* __restrict__ W3r,
                                                     ushort_t* __restrict__ Wb1, ushort_t* __restrict__ Wb2,
                                                     ushort_t* __restrict__ Wb3) {
    int t = threadIdx.x;
    if (blockIdx.x < 16) {
        // per-graph CSR build (count + scan + fill), graph b owns [b*EPG, (b+1)*EPG)
        __shared__ int cnt[1024];
        __shared__ int scanb[1024];
        int b = blockIdx.x;
        int e0 = b * EPG_;
        cnt[t] = 0;
        __syncthreads();
        for (int e = e0 + t; e < e0 + EPG_; e += 1024)
            atomicAdd(&cnt[ei[E_ + e] - b * NP_], 1);
        __syncthreads();
        int v = cnt[t];
        scanb[t] = v;
        __syncthreads();
        for (int off = 1; off < 1024; off <<= 1) {
            int tv = (t >= off) ? scanb[t - off] : 0;
            __syncthreads();
            scanb[t] += tv;
            __syncthreads();
        }
        int excl = scanb[t] - v;
        counts[b * NP_ + t] = v;
        offsets[b * NP_ + t] = e0 + excl;
        cnt[t] = excl;                     // becomes cursor
        __syncthreads();
        for (int e = e0 + t; e < e0 + EPG_; e += 1024) {
            int s = ei[e];
            int dloc = ei[E_ + e] - b * NP_;
            int pos = atomicAdd(&cnt[dloc], 1);
            adj[e0 + pos] = s;
        }
        return;
    }
    if (blockIdx.x < 19) {
        const float* p = blockIdx.x == 16 ? p1 : (blockIdx.x == 17 ? p2 : p3);
        __shared__ float red[1024];
        float a = p[t];
        red[t] = a * a;
        __syncthreads();
        for (int s = 512; s > 0; s >>= 1) {
            if (t < s) red[t] += red[t + s];
            __syncthreads();
        }
        if (t == 0) pnout[blockIdx.x - 16] = sqrtf(red[0]);
        return;
    }
    int idx = (blockIdx.x - 19) * 1024 + t;     // [0, 512K + 1M + 1M)
    if (idx >= 524288 + 1048576 + 1048576) return;
    const float *Wl, *Wr; ushort_t* Wbig; int K;
    if (idx < 524288) { Wl = W1l; Wr = W1r; Wbig = Wb1; K = 512; }
    else if (idx < 524288 + 1048576) { idx -= 524288; Wl = W2l; Wr = W2r; Wbig = Wb2; K = 1024; }
    else { idx -= 524288 + 1048576; Wl = W3l; Wr = W3r; Wbig = Wb3; K = 1024; }
    int n = idx / K;
    int k = idx - n * K;
    ushort_t* row = Wbig + (size_t)n * (4 * K);
    float a = Wl[idx];
    ushort_t ah = f2bf(a);
    row[k] = ah;
    row[K + k] = f2bf(a - bf2f(ah));
    float b = Wr[idx];
    ushort_t bh = f2bf(b);
    row[2 * K + k] = bh;
    row[3 * K + k] = f2bf(b - bf2f(bh));
}

// ---------------- aggregation + pack (col-split halves, XCD-pinned) ----------------
// Abig row (4K cols bf16): [agg_hi(K) | agg_lo(K) | cur_hi(K) | cur_lo(K)]

// Layer 1: source = x (K=512). 128 thr: 2 nodes x 64 float4 cols (one half).
__global__ __launch_bounds__(128) void agg1_k512(const float* __restrict__ x,
                                                 const int* __restrict__ adj,
                                                 const int* __restrict__ offsets,
                                                 const int* __restrict__ counts,
                                                 ushort_t* __restrict__ Abig) {
    int gid = blockIdx.x;
    int xcd = gid & 7;
    int u = gid >> 3;
    int half = u & 1;
    int pi = u >> 1;
    int gsel = (pi >= 512) ? 1 : 0;
    int g = xcd + (gsel << 3);
    int node = g * 1024 + (pi - (gsel << 9)) * 2 + (threadIdx.x >> 6);
    int c = threadIdx.x & 63;
    int col4 = half * 64 + c;
    int start = offsets[node], cnt = counts[node];
    float d = fmaxf((float)cnt, 1.0f);
    const float4* xb = (const float4*)x;
    float ax = 0.f, ay = 0.f, az = 0.f, aw = 0.f;
    int j = 0;
    for (; j + 8 <= cnt; j += 8) {
        int si[8];
#pragma unroll
        for (int q = 0; q < 8; ++q) si[q] = adj[start + j + q];
        float4 vv[8];
#pragma unroll
        for (int q = 0; q < 8; ++q) vv[q] = xb[(size_t)si[q] * 128 + col4];
#pragma unroll
        for (int q = 0; q < 8; ++q) {
            ax += vv[q].x; ay += vv[q].y; az += vv[q].z; aw += vv[q].w;
        }
    }
    for (; j + 4 <= cnt; j += 4) {
        int s0 = adj[start + j + 0], s1 = adj[start + j + 1];
        int s2 = adj[start + j + 2], s3 = adj[start + j + 3];
        float4 v0 = xb[(size_t)s0 * 128 + col4];
        float4 v1 = xb[(size_t)s1 * 128 + col4];
        float4 v2 = xb[(size_t)s2 * 128 + col4];
        float4 v3 = xb[(size_t)s3 * 128 + col4];
        ax += (v0.x + v1.x) + (v2.x + v3.x);
        ay += (v0.y + v1.y) + (v2.y + v3.y);
        az += (v0.z + v1.z) + (v2.z + v3.z);
        aw += (v0.w + v1.w) + (v2.w + v3.w);
    }
    for (; j < cnt; ++j) {
        float4 v = xb[(size_t)adj[start + j] * 128 + col4];
        ax += v.x; ay += v.y; az += v.z; aw += v.w;
    }
    float inv = 1.0f / d;
    float4 cv = xb[(size_t)node * 128 + col4];
    ushort_t* row = Abig + (size_t)node * 2048;
    int f = col4 * 4;
    ushort4 mh, ml, ch, cl;
    split1(ax * inv, mh.x, ml.x); split1(ay * inv, mh.y, ml.y);
    split1(az * inv, mh.z, ml.z); split1(aw * inv, mh.w, ml.w);
    split1(cv.x, ch.x, cl.x); split1(cv.y, ch.y, cl.y);
    split1(cv.z, ch.z, cl.z); split1(cv.w, ch.w, cl.w);
    *(ushort4*)&row[f]        = mh;
    *(ushort4*)&row[512 + f]  = ml;
    *(ushort4*)&row[1024 + f] = ch;
    *(ushort4*)&row[1536 + f] = cl;
}

// Layers 2/3: source = gated prev-layer h via (old_idx, vals). K=1024.
// Blocks [0, 32*n_per): aggregation. Blocks >= 32*n_per: zero one padded Abig row each.
template<int LAYER>
__global__ __launch_bounds__(128) void agg23_k1024(const float* __restrict__ h,
                                                   const int* __restrict__ adj,
                                                   const int* __restrict__ offsets,
                                                   const int* __restrict__ counts,
                                                   const int* __restrict__ old_idx,
                                                   const float* __restrict__ vals,
                                                   ushort_t* __restrict__ Abig,
                                                   int n_per, int M, int npad) {
    int gid = blockIdx.x;
    if (gid >= 32 * n_per) {
        // pad-zero row M + r (r in [0, npad))
        int r = gid - 32 * n_per;
        if (r < npad) {
            uint4* row = (uint4*)(Abig + (size_t)(M + r) * 4096);   // 512 uint4
#pragma unroll
            for (int q = 0; q < 4; ++q) row[threadIdx.x + q * 128] = (uint4){0, 0, 0, 0};
        }
        return;
    }
    int xcd = gid & 7;
    int u = gid >> 3;
    int half = u & 1;
    int nl = u >> 1;
    int gsel = (nl >= n_per) ? 1 : 0;
    int g = xcd + (gsel << 3);
    int node = g * n_per + nl - gsel * n_per;
    int c = threadIdx.x;
    int col4 = half * 128 + c;
    int start = offsets[node], cnt = counts[node];
    float d = fmaxf((float)cnt, 1.0f);
    const float4* hb = (const float4*)h;
    float ax = 0.f, ay = 0.f, az = 0.f, aw = 0.f;
    int j = 0;
    for (; j + 8 <= cnt; j += 8) {
        int si[8];
#pragma unroll
        for (int q = 0; q < 8; ++q) si[q] = adj[start + j + q];
        int oi[8]; float wi[8];
#pragma unroll
        for (int q = 0; q < 8; ++q) { oi[q] = old_idx[si[q]]; wi[q] = vals[si[q]]; }
        float4 vv[8];
#pragma unroll
        for (int q = 0; q < 8; ++q) vv[q] = hb[(size_t)oi[q] * 256 + col4];
#pragma unroll
        for (int q = 0; q < 8; ++q) {
            ax += wi[q] * vv[q].x; ay += wi[q] * vv[q].y;
            az += wi[q] * vv[q].z; aw += wi[q] * vv[q].w;
        }
    }
    for (; j + 4 <= cnt; j += 4) {
        int s0 = adj[start + j + 0], s1 = adj[start + j + 1];
        int s2 = adj[start + j + 2], s3 = adj[start + j + 3];
        int o0 = old_idx[s0], o1 = old_idx[s1], o2 = old_idx[s2], o3 = old_idx[s3];
        float w0 = vals[s0], w1 = vals[s1], w2 = vals[s2], w3 = vals[s3];
        float4 v0 = hb[(size_t)o0 * 256 + col4];
        float4 v1 = hb[(size_t)o1 * 256 + col4];
        float4 v2 = hb[(size_t)o2 * 256 + col4];
        float4 v3 = hb[(size_t)o3 * 256 + col4];
        ax += (w0 * v0.x + w1 * v1.x) + (w2 * v2.x + w3 * v3.x);
        ay += (w0 * v0.y + w1 * v1.y) + (w2 * v2.y + w3 * v3.y);
        az += (w0 * v0.z + w1 * v1.z) + (w2 * v2.z + w3 * v3.z);
        aw += (w0 * v0.w + w1 * v1.w) + (w2 * v2.w + w3 * v3.w);
    }
    for (; j < cnt; ++j) {
        int s = adj[start + j];
        int o = old_idx[s];
        float w = vals[s];
        float4 v = hb[(size_t)o * 256 + col4];
        ax += w * v.x; ay += w * v.y; az += w * v.z; aw += w * v.w;
    }
    float inv = 1.0f / d;
    int on = old_idx[node];
    float vn = vals[node];
    float4 cv = hb[(size_t)on * 256 + col4];
    cv.x *= vn; cv.y *= vn; cv.z *= vn; cv.w *= vn;
    ushort_t* row = Abig + (size_t)node * 4096;
    int f = col4 * 4;
    ushort4 mh, ml, ch, cl;
    split1(ax * inv, mh.x, ml.x); split1(ay * inv, mh.y, ml.y);
    split1(az * inv, mh.z, ml.z); split1(aw * inv, mh.w, ml.w);
    split1(cv.x, ch.x, cl.x); split1(cv.y, ch.y, cl.y);
    split1(cv.z, ch.z, cl.z); split1(cv.w, ch.w, cl.w);
    *(ushort4*)&row[f]        = mh;
    *(ushort4*)&row[1024 + f] = ml;
    *(ushort4*)&row[2048 + f] = ch;
    *(ushort4*)&row[3072 + f] = cl;
}

// ---------------- MFMA GEMM: 256x256 tile, 8 waves, 1-barrier/chunk + conflict-free LDS layout ----
// A row (LD=4K cols bf16): [agg_hi K | agg_lo K | cur_hi K | cur_lo K]; W packed identically.
// LDS: 2 bufs x 4 planes (AH,AL,BH,BL; 8192 ushorts each) = 128 KiB.
// NEW (R4): fragment-major LDS layout so every ds_read_b128 is lane-linear (zero bank conflict,
// m134 pattern). Plane ushort index S*8+e holds global (row = ((S>>6)<<4)|(S&15),
// k = ((S>>4)&3)*8 + e). Achieved by permuting the gll16 GLOBAL SOURCE per thread (LDS dest
// stays linear, rule #21); reads become Lr[group*512 + lane*8] -- wave-uniform base + lane*16B.
// Fragment per lane = (row = lane&15, k-quad = lane>>4): identical MFMA inputs as before ->
// bitwise-identical C. Schedule unchanged from R3 (1 barrier/chunk, VMW(0) on stale DMA).

#define STR_(x) #x
#define VMW2_(n) asm volatile("s_waitcnt vmcnt(" STR_(n) ")" ::: "memory")
#define VMW(n) VMW2_(n)
#define BARM() do { __builtin_amdgcn_s_barrier(); asm volatile("" ::: "memory"); } while (0)

// 8 gll16 per chunk: planes AH(0), AL(8192), BH(16384), BL(24576); halves h0/h1 at +0/+4096.
#define STG8(Lw_, cs_) do {                                                         \
    gll16(A0s + (cs_), (Lw_) + tid * 8);                                            \
    gll16(A1s + (cs_), (Lw_) + 4096 + tid * 8);                                     \
    gll16(B0s + (cs_), (Lw_) + 16384 + tid * 8);                                    \
    gll16(B1s + (cs_), (Lw_) + 20480 + tid * 8);                                    \
    gll16(A0s + KK + (cs_), (Lw_) + 8192 + tid * 8);                                \
    gll16(A1s + KK + (cs_), (Lw_) + 12288 + tid * 8);                               \
    gll16(B0s + KK + (cs_), (Lw_) + 24576 + tid * 8);                               \
    gll16(B1s + KK + (cs_), (Lw_) + 28672 + tid * 8);                               \
} while (0)

#define MFQ(I0, Aarr, A0, Barr)                                                     \
    _Pragma("unroll")                                                               \
    for (int ii = 0; ii < 4; ++ii) {                                                \
        _Pragma("unroll")                                                           \
        for (int jj = 0; jj < 4; ++jj)                                              \
            acc[(I0) + ii][jj] = __builtin_amdgcn_mfma_f32_16x16x32_bf16(           \
                Aarr[(A0) + ii], Barr[jj], acc[(I0) + ii][jj], 0, 0, 0);            \
    }

#define CHUNK(t_, b_, stg_) do {                                                    \
    int cs_ = ((t_) + 1 < NC2) ? ((t_) + 1) * 32 : 2 * KK + ((t_) + 1 - NC2) * 32;  \
    const ushort_t* Lr = L + (b_) * 32768;                                          \
    ushort_t* Lw = L + (1 - (b_)) * 32768;                                          \
    VMW(0);                                                                         \
    BARM();                                                                         \
    bf16x8 ah[8], al[8], bh[4], bl[4];                                              \
    _Pragma("unroll") for (int q = 0; q < 8; ++q)                                   \
        ah[q] = *(const bf16x8*)&Lr[wm * 4096 + q * 512 + ln8];                     \
    _Pragma("unroll") for (int q = 0; q < 4; ++q)                                   \
        bh[q] = *(const bf16x8*)&Lr[16384 + wn * 2048 + q * 512 + ln8];             \
    if (stg_) { STG8(Lw, cs_); }                                                    \
    _Pragma("unroll") for (int q = 0; q < 8; ++q)                                   \
        al[q] = *(const bf16x8*)&Lr[8192 + wm * 4096 + q * 512 + ln8];              \
    _Pragma("unroll") for (int q = 0; q < 4; ++q)                                   \
        bl[q] = *(const bf16x8*)&Lr[24576 + wn * 2048 + q * 512 + ln8];             \
    __builtin_amdgcn_s_setprio(1);                                                  \
    MFQ(0, ah, 0, bh);                                                              \
    MFQ(4, ah, 4, bh);                                                              \
    __builtin_amdgcn_s_setprio(0);                                                  \
    __builtin_amdgcn_s_setprio(1);                                                  \
    MFQ(0, al, 0, bh);                                                              \
    MFQ(4, al, 4, bh);                                                              \
    MFQ(0, ah, 0, bl);                                                              \
    MFQ(4, ah, 4, bl);                                                              \
    __builtin_amdgcn_s_setprio(0);                                                  \
} while (0)

template<int KK>
__global__ __launch_bounds__(512, 2) void gemm256(const ushort_t* __restrict__ Ab,
                                                  const ushort_t* __restrict__ Wb,
                                                  const float* __restrict__ bias,
                                                  float* __restrict__ C,
                                                  float* __restrict__ sp,
                                                  const float* __restrict__ pvec,
                                                  int npanels) {
    constexpr int LD  = 4 * KK;
    constexpr int NC  = KK / 16;     // 32-k chunks over [agg|cur]
    constexpr int NC2 = KK / 32;
    __shared__ ushort_t L[65536];    // 2 bufs x 4 planes x 8192 ushorts = 128 KiB

    int tid = threadIdx.x;
    int lane = tid & 63;
    int ln8 = lane * 8;
    int w = tid >> 6;
    int wm = w >> 2, wn = w & 3;     // 2x4 wave grid; wave tile 128x64

    // XCD-contiguous block mapping (nblocks divisible by 8: 256/208/176)
    int nb = npanels * 4;
    int per = nb >> 3;
    int bp = (blockIdx.x & 7) * per + (blockIdx.x >> 3);
    int panel = bp >> 2, cb = bp & 3;
    int m0 = panel * 256, n0 = cb * 256;

    // staging source addressing: thread writes plane ushorts [S*8, S*8+8) for S = tid (+512 for h1)
    // -> must fetch global (row = ((S>>6)<<4)|(S&15), k-quad = (S>>4)&3)
    int S0 = tid, S1 = tid + 512;
    int rA0 = ((S0 >> 6) << 4) | (S0 & 15);
    int qA0 = (S0 >> 4) & 3;
    int rA1 = ((S1 >> 6) << 4) | (S1 & 15);
    int qA1 = (S1 >> 4) & 3;
    const ushort_t* A0s = Ab + (size_t)(m0 + rA0) * LD + qA0 * 8;
    const ushort_t* A1s = Ab + (size_t)(m0 + rA1) * LD + qA1 * 8;
    const ushort_t* B0s = Wb + (size_t)(n0 + rA0) * LD + qA0 * 8;
    const ushort_t* B1s = Wb + (size_t)(n0 + rA1) * LD + qA1 * 8;

    f32x4 acc[8][4];
#pragma unroll
    for (int i = 0; i < 8; ++i)
#pragma unroll
        for (int j = 0; j < 4; ++j) acc[i][j] = (f32x4){0.f, 0.f, 0.f, 0.f};

    // prologue: stage chunk 0 into buf 0
    {
        ushort_t* Lw0 = L;
        STG8(Lw0, 0);
    }

#pragma unroll 1
    for (int t = 0; t < NC - 2; t += 2) {
        CHUNK(t,     0, 1);
        CHUNK(t + 1, 1, 1);
    }
    CHUNK(NC - 2, 0, 1);
    CHUNK(NC - 1, 1, 0);             // last chunk: no staging

    // ---- epilogue: bias + relu + C write + score partials ----
    float bj[4], pj[4];
#pragma unroll
    for (int j = 0; j < 4; ++j) {
        int col = n0 + wn * 64 + j * 16 + (lane & 15);
        bj[j] = bias[col];
        pj[j] = pvec[col];
    }
    int slot = cb * 4 + wn;
#pragma unroll
    for (int i = 0; i < 8; ++i) {
        int row0 = m0 + wm * 128 + i * 16 + (lane >> 4) * 4;
        float sacc[4] = {0.f, 0.f, 0.f, 0.f};
#pragma unroll
        for (int j = 0; j < 4; ++j) {
            int col = n0 + wn * 64 + j * 16 + (lane & 15);
#pragma unroll
            for (int r = 0; r < 4; ++r) {
                float v = acc[i][j][r] + bj[j];
                v = v > 0.f ? v : 0.f;
                C[(size_t)(row0 + r) * 1024 + col] = v;
                sacc[r] += v * pj[j];
            }
        }
#pragma unroll
        for (int r = 0; r < 4; ++r) {
            float sv_ = sacc[r];
            sv_ += __shfl_xor(sv_, 1);
            sv_ += __shfl_xor(sv_, 2);
            sv_ += __shfl_xor(sv_, 4);
            sv_ += __shfl_xor(sv_, 8);
            if ((lane & 15) == 0) sp[slot * SPROWS_ + row0 + r] = sv_;
        }
    }
}

// ---------------- tail: 9 blocks/graph (R8-proven, 1024 threads) ----------------
// roles 0-7: rank-select (redundant) + readout of a 32-float4-col slice.
// role 8:    rank-select + old_idx/vals write + edge remap + CSR rebuild.
// FIRST also selects '=' vs '+=' on the out write (removes d_out memset).

template<int FIRST>
__global__ __launch_bounds__(1024) void tail_kernel(const float* __restrict__ sp,
                                                    const float* __restrict__ pn,
                                                    const float* __restrict__ h,
                                                    float* __restrict__ out,
                                                    int n, int k,
                                                    int* __restrict__ old_idx, float* __restrict__ vals,
                                                    const int* __restrict__ ei,
                                                    int* __restrict__ esrc, int* __restrict__ edst,
                                                    int* __restrict__ emask,
                                                    int* __restrict__ counts, int* __restrict__ offsets,
                                                    int* __restrict__ adj, int do_edges) {
    __shared__ float sv[1024];
    __shared__ int   rmap[1024];
    __shared__ int   oi_s[1024];
    __shared__ float vv_s[1024];
    __shared__ float4 rmx[32][32];
    __shared__ float4 rsm[32][32];
    int b = blockIdx.x / 9, role = blockIdx.x % 9;
    int t = threadIdx.x;
    if (role == 8 && !do_edges) return;

    // phase 1: sum score partials, rank-select (stable descending top-k)
    float mine = -INFINITY;
    if (t < n) {
        int base = b * n + t;
        float s0 = 0.f;
#pragma unroll
        for (int c = 0; c < 16; ++c) s0 += sp[c * SPROWS_ + base];
        mine = s0;
    }
    sv[t] = mine;
    __syncthreads();
    int rank = 0;
#pragma unroll 4
    for (int j = 0; j < 1024; ++j) {
        float o = sv[j];
        rank += (o > mine) || (o == mine && j < t);
    }
    bool kept = (t < n) && (rank < k);
    rmap[t] = kept ? rank : -1;
    if (kept) {
        float tv = tanhf(mine / pn[0]);
        oi_s[rank] = b * n + t;
        vv_s[rank] = tv;
        if (role == 8) {
            old_idx[b * k + rank] = b * n + t;
            vals[b * k + rank] = tv;
        }
    }
    __syncthreads();

    if (role < 8) {
        // readout slice: 32 float4 cols, 32 row-groups
        int c32 = t & 31, g = t >> 5;
        int col4 = role * 32 + c32;
        const float4* hb = (const float4*)h;
        float4 mx = {-INFINITY, -INFINITY, -INFINITY, -INFINITY};
        float4 sm = {0.f, 0.f, 0.f, 0.f};
        for (int i = g; i < k; i += 32) {
            int o = oi_s[i];
            float wgt = vv_s[i];
            float4 v = hb[(size_t)o * 256 + col4];
            v.x *= wgt; v.y *= wgt; v.z *= wgt; v.w *= wgt;
            mx.x = fmaxf(mx.x, v.x); mx.y = fmaxf(mx.y, v.y);
            mx.z = fmaxf(mx.z, v.z); mx.w = fmaxf(mx.w, v.w);
            sm.x += v.x; sm.y += v.y; sm.z += v.z; sm.w += v.w;
        }
        rmx[g][c32] = mx; rsm[g][c32] = sm;
        __syncthreads();
        for (int s = 16; s > 0; s >>= 1) {
            if (g < s) {
                float4 om = rmx[g + s][c32], os = rsm[g + s][c32];
                float4 m = rmx[g][c32], ss2 = rsm[g][c32];
                m.x = fmaxf(m.x, om.x); m.y = fmaxf(m.y, om.y);
                m.z = fmaxf(m.z, om.z); m.w = fmaxf(m.w, om.w);
                ss2.x += os.x; ss2.y += os.y; ss2.z += os.z; ss2.w += os.w;
                rmx[g][c32] = m; rsm[g][c32] = ss2;
            }
            __syncthreads();
        }
        if (g == 0) {
            float4 m = rmx[0][c32], ss2 = rsm[0][c32];
            float invk = 1.0f / (float)k;
            float* o0 = out + (size_t)b * 2048 + col4 * 4;
            float* o1 = o0 + 1024;
            if (FIRST) {
                o0[0] = m.x; o0[1] = m.y; o0[2] = m.z; o0[3] = m.w;
                o1[0] = ss2.x * invk; o1[1] = ss2.y * invk;
                o1[2] = ss2.z * invk; o1[3] = ss2.w * invk;
            } else {
                o0[0] += m.x; o0[1] += m.y; o0[2] += m.z; o0[3] += m.w;
                o1[0] += ss2.x * invk; o1[1] += ss2.y * invk;
                o1[2] += ss2.z * invk; o1[3] += ss2.w * invk;
            }
        }
        return;
    }

    // role 8: edge phases
    __shared__ int cnt_s[1024];
    cnt_s[t] = 0;
    __syncthreads();
    int e0 = b * EPG_;
    // pass A: count new in-degrees
    for (int e = e0 + t; e < e0 + EPG_; e += 1024) {
        int ms = FIRST ? 1 : emask[e];
        if (ms) {
            int s = FIRST ? ei[e] : esrc[e];
            int dd = FIRST ? ei[E_ + e] : edst[e];
            int ns = rmap[s - b * n];
            int nd = rmap[dd - b * n];
            if (ns >= 0 && nd >= 0) atomicAdd(&cnt_s[nd], 1);
        }
    }
    __syncthreads();
    // scan over k
    int v = (t < k) ? cnt_s[t] : 0;
    oi_s[t] = v;
    __syncthreads();
    for (int off = 1; off < 1024; off <<= 1) {
        int tv = (t >= off) ? oi_s[t - off] : 0;
        __syncthreads();
        oi_s[t] += tv;
        __syncthreads();
    }
    int excl = oi_s[t] - v;
    if (t < k) {
        counts[b * k + t] = v;
        offsets[b * k + t] = e0 + excl;
        cnt_s[t] = excl;               // becomes fill cursor
    }
    __syncthreads();
    // pass B: remap + write final edges + fill adj
    for (int e = e0 + t; e < e0 + EPG_; e += 1024) {
        int ms = FIRST ? 1 : emask[e];
        if (ms) {
            int s = FIRST ? ei[e] : esrc[e];
            int dd = FIRST ? ei[E_ + e] : edst[e];
            int ns = rmap[s - b * n];
            int nd = rmap[dd - b * n];
            if (ns >= 0 && nd >= 0) {
                int gs = b * k + ns;
                esrc[e] = gs;
                edst[e] = b * k + nd;
                if (FIRST) emask[e] = 1;
                int pos = atomicAdd(&cnt_s[nd], 1);
                adj[e0 + pos] = gs;
            } else {
                emask[e] = 0;
            }
        } else if (FIRST) {
            emask[e] = 0;
        }
    }
}

// ---------------- host-side ----------------

extern "C" void kernel_launch(void* const* d_in, const int* in_sizes, int n_in,
                              void* d_out, int out_size, void* d_ws, size_t ws_size,
                              hipStream_t stream) {
    const float* x   = (const float*)d_in[0];
    const int*   ei  = (const int*)d_in[1];
    const float* W1l = (const float*)d_in[3];
    const float* b1  = (const float*)d_in[4];
    const float* W1r = (const float*)d_in[5];
    const float* p1  = (const float*)d_in[6];
    const float* W2l = (const float*)d_in[7];
    const float* b2  = (const float*)d_in[8];
    const float* W2r = (const float*)d_in[9];
    const float* p2  = (const float*)d_in[10];
    const float* W3l = (const float*)d_in[11];
    const float* b3  = (const float*)d_in[12];
    const float* W3r = (const float*)d_in[13];
    const float* p3  = (const float*)d_in[14];
    float* out = (float*)d_out;

    char* ws = (char*)d_ws;
    size_t off = 0;
    float* bufOut = (float*)(ws + off); off += (size_t)MP1_ * 1024 * 4;            // 64 MB
    ushort_t* Abig = (ushort_t*)(ws + off); off += (size_t)MP2_ * 4096 * 2;        // 109 MB
    ushort_t* Wb1 = (ushort_t*)(ws + off); off += (size_t)1024 * 2048 * 2;         // 4 MB
    ushort_t* Wb2 = (ushort_t*)(ws + off); off += (size_t)1024 * 4096 * 2;         // 8 MB
    ushort_t* Wb3 = (ushort_t*)(ws + off); off += (size_t)1024 * 4096 * 2;         // 8 MB
    float* sp = (float*)(ws + off); off += (size_t)16 * SPROWS_ * 4;               // 1 MB
    char* misc = ws + off;
    int*   counts = (int*)(misc + 0 * 65536);
    int*   offsets= (int*)(misc + 1 * 65536);
    int*   old_idx= (int*)(misc + 2 * 65536);
    float* vals   = (float*)(misc + 3 * 65536);
    float* pnormv = (float*)(misc + 4 * 65536);
    int*   adj    = (int*)(misc + 5 * 65536);
    int*   esrc   = (int*)(misc + 5 * 65536 + 1 * 1048576);
    int*   edst   = (int*)(misc + 5 * 65536 + 2 * 1048576);
    int*   emask  = (int*)(misc + 5 * 65536 + 3 * 1048576);

    // prep2: csr0 (16 blocks) + pnorms (3) + weight packing (2560)
    prep2_kernel<<<19 + (524288 + 2 * 1048576) / 1024, 1024, 0, stream>>>(
        ei, counts, offsets, adj, p1, p2, p3, pnormv,
        W1l, W1r, W2l, W2r, W3l, W3r, Wb1, Wb2, Wb3);

    // ---- layer 1 (K=512, n=1024 -> k=820) ----
    agg1_k512<<<16384, 128, 0, stream>>>(x, adj, offsets, counts, Abig);
    gemm256<512><<<(MP1_ / 256) * 4, 512, 0, stream>>>(Abig, Wb1, b1, bufOut, sp, p1, MP1_ / 256);
    tail_kernel<1><<<B_ * 9, 1024, 0, stream>>>(sp, pnormv + 0, bufOut, out, NP_, K1_,
                                                old_idx, vals, ei, esrc, edst, emask,
                                                counts, offsets, adj, 1);

    // ---- layer 2 (K=1024, n=820 -> k=656); pad rows zeroed by extra agg blocks ----
    agg23_k1024<2><<<32 * K1_ + (MP2_ - M2_), 128, 0, stream>>>(
        bufOut, adj, offsets, counts, old_idx, vals, Abig, K1_, M2_, MP2_ - M2_);
    gemm256<1024><<<(MP2_ / 256) * 4, 512, 0, stream>>>(Abig, Wb2, b2, bufOut, sp, p2, MP2_ / 256);
    tail_kernel<0><<<B_ * 9, 1024, 0, stream>>>(sp, pnormv + 1, bufOut, out, K1_, K2_,
                                                old_idx, vals, ei, esrc, edst, emask,
                                                counts, offsets, adj, 1);

    // ---- layer 3 (K=1024, n=656 -> k=525) ----
    agg23_k1024<3><<<32 * K2_ + (MP3_ - M3_), 128, 0, stream>>>(
        bufOut, adj, offsets, counts, old_idx, vals, Abig, K2_, M3_, MP3_ - M3_);
    gemm256<1024><<<(MP3_ / 256) * 4, 512, 0, stream>>>(Abig, Wb3, b3, bufOut, sp, p3, MP3_ / 256);
    tail_kernel<0><<<B_ * 9, 1024, 0, stream>>>(sp, pnormv + 2, bufOut, out, K2_, K3_,
                                                old_idx, vals, ei, esrc, edst, emask,
                                                counts, offsets, adj, 0);
}

// Round 5
// 737.944 us; speedup vs baseline: 1.1284x; 1.1284x over previous
//
#include <hip/hip_runtime.h>
#include <math.h>

// Problem constants (fixed by reference)
#define B_    16
#define NP_   1024
#define FEAT_ 512
#define H_    1024
#define E_    262144          // B*NP*DEG
#define EPG_  16384           // edges per graph (edge list is graph-sorted)
#define K1_   820             // ceil(0.8*1024)
#define K2_   656             // ceil(0.8*820)
#define K3_   525             // ceil(0.8*656)
#define M1_   16384           // B*NP
#define M2_   13120           // B*K1
#define M3_   10496           // B*K2
// padded row counts: multiples of 256 (256-row GEMM panels), panel*4 divisible by 8
#define MP1_  16384           // 64 panels
#define MP2_  13312           // 52 panels
#define MP3_  11264           // 44 panels
#define SPROWS_ 16384         // scoresPart row stride

typedef unsigned short ushort_t;
typedef __bf16 bf16x8 __attribute__((ext_vector_type(8)));
typedef float f32x4 __attribute__((ext_vector_type(4)));

// ---- bf16 split helpers (RNE) ----
__device__ inline ushort_t f2bf(float f) {
    unsigned u = __float_as_uint(f);
    u += 0x7FFF + ((u >> 16) & 1);
    return (ushort_t)(u >> 16);
}
__device__ inline float bf2f(ushort_t h) {
    return __uint_as_float(((unsigned)h) << 16);
}
__device__ inline void split1(float v, ushort_t& hi, ushort_t& lo) {
    hi = f2bf(v);
    lo = f2bf(v - bf2f(hi));
}

__device__ inline void gll16(const void* g, void* l) {
    __builtin_amdgcn_global_load_lds((__attribute__((address_space(1))) void*)g,
                                     (__attribute__((address_space(3))) void*)l, 16, 0, 0);
}

// ---------------- prep2: csr0 (blocks 0-15) + pnorms (16-18) + weight pack (19+) ----------------

__global__ __launch_bounds__(1024) void prep2_kernel(const int* __restrict__ ei,
                                                     int* __restrict__ counts,
                                                     int* __restrict__ offsets,
                                                     int* __restrict__ adj,
                                                     const float* __restrict__ p1,
                                                     const float* __restrict__ p2,
                                                     const float* __restrict__ p3,
                                                     float* __restrict__ pnout,
                                                     const float* __restrict__ W1l, const float* __restrict__ W1r,
                                                     const float* __restrict__ W2l, const float* __restrict__ W2r,
                                                     const float* __restrict__ W3l, const float* __restrict__ W3r,
                                                     ushort_t* __restrict__ Wb1, ushort_t* __restrict__ Wb2,
                                                     ushort_t* __restrict__ Wb3) {
    int t = threadIdx.x;
    if (blockIdx.x < 16) {
        // per-graph CSR build (count + scan + fill), graph b owns [b*EPG, (b+1)*EPG)
        __shared__ int cnt[1024];
        __shared__ int scanb[1024];
        int b = blockIdx.x;
        int e0 = b * EPG_;
        cnt[t] = 0;
        __syncthreads();
        for (int e = e0 + t; e < e0 + EPG_; e += 1024)
            atomicAdd(&cnt[ei[E_ + e] - b * NP_], 1);
        __syncthreads();
        int v = cnt[t];
        scanb[t] = v;
        __syncthreads();
        for (int off = 1; off < 1024; off <<= 1) {
            int tv = (t >= off) ? scanb[t - off] : 0;
            __syncthreads();
            scanb[t] += tv;
            __syncthreads();
        }
        int excl = scanb[t] - v;
        counts[b * NP_ + t] = v;
        offsets[b * NP_ + t] = e0 + excl;
        cnt[t] = excl;                     // becomes cursor
        __syncthreads();
        for (int e = e0 + t; e < e0 + EPG_; e += 1024) {
            int s = ei[e];
            int dloc = ei[E_ + e] - b * NP_;
            int pos = atomicAdd(&cnt[dloc], 1);
            adj[e0 + pos] = s;
        }
        return;
    }
    if (blockIdx.x < 19) {
        const float* p = blockIdx.x == 16 ? p1 : (blockIdx.x == 17 ? p2 : p3);
        __shared__ float red[1024];
        float a = p[t];
        red[t] = a * a;
        __syncthreads();
        for (int s = 512; s > 0; s >>= 1) {
            if (t < s) red[t] += red[t + s];
            __syncthreads();
        }
        if (t == 0) pnout[blockIdx.x - 16] = sqrtf(red[0]);
        return;
    }
    int idx = (blockIdx.x - 19) * 1024 + t;     // [0, 512K + 1M + 1M)
    if (idx >= 524288 + 1048576 + 1048576) return;
    const float *Wl, *Wr; ushort_t* Wbig; int K;
    if (idx < 524288) { Wl = W1l; Wr = W1r; Wbig = Wb1; K = 512; }
    else if (idx < 524288 + 1048576) { idx -= 524288; Wl = W2l; Wr = W2r; Wbig = Wb2; K = 1024; }
    else { idx -= 524288 + 1048576; Wl = W3l; Wr = W3r; Wbig = Wb3; K = 1024; }
    int n = idx / K;
    int k = idx - n * K;
    ushort_t* row = Wbig + (size_t)n * (4 * K);
    float a = Wl[idx];
    ushort_t ah = f2bf(a);
    row[k] = ah;
    row[K + k] = f2bf(a - bf2f(ah));
    float b = Wr[idx];
    ushort_t bh = f2bf(b);
    row[2 * K + k] = bh;
    row[3 * K + k] = f2bf(b - bf2f(bh));
}

// ---------------- aggregation + pack (col-split halves, XCD-pinned) ----------------
// Abig row (4K cols bf16): [agg_hi(K) | agg_lo(K) | cur_hi(K) | cur_lo(K)]

// Layer 1: source = x (K=512). 128 thr: 2 nodes x 64 float4 cols (one half).
__global__ __launch_bounds__(128) void agg1_k512(const float* __restrict__ x,
                                                 const int* __restrict__ adj,
                                                 const int* __restrict__ offsets,
                                                 const int* __restrict__ counts,
                                                 ushort_t* __restrict__ Abig) {
    int gid = blockIdx.x;
    int xcd = gid & 7;
    int u = gid >> 3;
    int half = u & 1;
    int pi = u >> 1;
    int gsel = (pi >= 512) ? 1 : 0;
    int g = xcd + (gsel << 3);
    int node = g * 1024 + (pi - (gsel << 9)) * 2 + (threadIdx.x >> 6);
    int c = threadIdx.x & 63;
    int col4 = half * 64 + c;
    int start = offsets[node], cnt = counts[node];
    float d = fmaxf((float)cnt, 1.0f);
    const float4* xb = (const float4*)x;
    float ax = 0.f, ay = 0.f, az = 0.f, aw = 0.f;
    int j = 0;
    for (; j + 8 <= cnt; j += 8) {
        int si[8];
#pragma unroll
        for (int q = 0; q < 8; ++q) si[q] = adj[start + j + q];
        float4 vv[8];
#pragma unroll
        for (int q = 0; q < 8; ++q) vv[q] = xb[(size_t)si[q] * 128 + col4];
#pragma unroll
        for (int q = 0; q < 8; ++q) {
            ax += vv[q].x; ay += vv[q].y; az += vv[q].z; aw += vv[q].w;
        }
    }
    for (; j + 4 <= cnt; j += 4) {
        int s0 = adj[start + j + 0], s1 = adj[start + j + 1];
        int s2 = adj[start + j + 2], s3 = adj[start + j + 3];
        float4 v0 = xb[(size_t)s0 * 128 + col4];
        float4 v1 = xb[(size_t)s1 * 128 + col4];
        float4 v2 = xb[(size_t)s2 * 128 + col4];
        float4 v3 = xb[(size_t)s3 * 128 + col4];
        ax += (v0.x + v1.x) + (v2.x + v3.x);
        ay += (v0.y + v1.y) + (v2.y + v3.y);
        az += (v0.z + v1.z) + (v2.z + v3.z);
        aw += (v0.w + v1.w) + (v2.w + v3.w);
    }
    for (; j < cnt; ++j) {
        float4 v = xb[(size_t)adj[start + j] * 128 + col4];
        ax += v.x; ay += v.y; az += v.z; aw += v.w;
    }
    float inv = 1.0f / d;
    float4 cv = xb[(size_t)node * 128 + col4];
    ushort_t* row = Abig + (size_t)node * 2048;
    int f = col4 * 4;
    ushort4 mh, ml, ch, cl;
    split1(ax * inv, mh.x, ml.x); split1(ay * inv, mh.y, ml.y);
    split1(az * inv, mh.z, ml.z); split1(aw * inv, mh.w, ml.w);
    split1(cv.x, ch.x, cl.x); split1(cv.y, ch.y, cl.y);
    split1(cv.z, ch.z, cl.z); split1(cv.w, ch.w, cl.w);
    *(ushort4*)&row[f]        = mh;
    *(ushort4*)&row[512 + f]  = ml;
    *(ushort4*)&row[1024 + f] = ch;
    *(ushort4*)&row[1536 + f] = cl;
}

// Layers 2/3: source = gated prev-layer h via (old_idx, vals). K=1024.
// Blocks [0, 32*n_per): aggregation. Blocks >= 32*n_per: zero one padded Abig row each.
template<int LAYER>
__global__ __launch_bounds__(128) void agg23_k1024(const float* __restrict__ h,
                                                   const int* __restrict__ adj,
                                                   const int* __restrict__ offsets,
                                                   const int* __restrict__ counts,
                                                   const int* __restrict__ old_idx,
                                                   const float* __restrict__ vals,
                                                   ushort_t* __restrict__ Abig,
                                                   int n_per, int M, int npad) {
    int gid = blockIdx.x;
    if (gid >= 32 * n_per) {
        // pad-zero row M + r (r in [0, npad))
        int r = gid - 32 * n_per;
        if (r < npad) {
            uint4* row = (uint4*)(Abig + (size_t)(M + r) * 4096);   // 512 uint4
#pragma unroll
            for (int q = 0; q < 4; ++q) row[threadIdx.x + q * 128] = (uint4){0, 0, 0, 0};
        }
        return;
    }
    int xcd = gid & 7;
    int u = gid >> 3;
    int half = u & 1;
    int nl = u >> 1;
    int gsel = (nl >= n_per) ? 1 : 0;
    int g = xcd + (gsel << 3);
    int node = g * n_per + nl - gsel * n_per;
    int c = threadIdx.x;
    int col4 = half * 128 + c;
    int start = offsets[node], cnt = counts[node];
    float d = fmaxf((float)cnt, 1.0f);
    const float4* hb = (const float4*)h;
    float ax = 0.f, ay = 0.f, az = 0.f, aw = 0.f;
    int j = 0;
    for (; j + 8 <= cnt; j += 8) {
        int si[8];
#pragma unroll
        for (int q = 0; q < 8; ++q) si[q] = adj[start + j + q];
        int oi[8]; float wi[8];
#pragma unroll
        for (int q = 0; q < 8; ++q) { oi[q] = old_idx[si[q]]; wi[q] = vals[si[q]]; }
        float4 vv[8];
#pragma unroll
        for (int q = 0; q < 8; ++q) vv[q] = hb[(size_t)oi[q] * 256 + col4];
#pragma unroll
        for (int q = 0; q < 8; ++q) {
            ax += wi[q] * vv[q].x; ay += wi[q] * vv[q].y;
            az += wi[q] * vv[q].z; aw += wi[q] * vv[q].w;
        }
    }
    for (; j + 4 <= cnt; j += 4) {
        int s0 = adj[start + j + 0], s1 = adj[start + j + 1];
        int s2 = adj[start + j + 2], s3 = adj[start + j + 3];
        int o0 = old_idx[s0], o1 = old_idx[s1], o2 = old_idx[s2], o3 = old_idx[s3];
        float w0 = vals[s0], w1 = vals[s1], w2 = vals[s2], w3 = vals[s3];
        float4 v0 = hb[(size_t)o0 * 256 + col4];
        float4 v1 = hb[(size_t)o1 * 256 + col4];
        float4 v2 = hb[(size_t)o2 * 256 + col4];
        float4 v3 = hb[(size_t)o3 * 256 + col4];
        ax += (w0 * v0.x + w1 * v1.x) + (w2 * v2.x + w3 * v3.x);
        ay += (w0 * v0.y + w1 * v1.y) + (w2 * v2.y + w3 * v3.y);
        az += (w0 * v0.z + w1 * v1.z) + (w2 * v2.z + w3 * v3.z);
        aw += (w0 * v0.w + w1 * v1.w) + (w2 * v2.w + w3 * v3.w);
    }
    for (; j < cnt; ++j) {
        int s = adj[start + j];
        int o = old_idx[s];
        float w = vals[s];
        float4 v = hb[(size_t)o * 256 + col4];
        ax += w * v.x; ay += w * v.y; az += w * v.z; aw += w * v.w;
    }
    float inv = 1.0f / d;
    int on = old_idx[node];
    float vn = vals[node];
    float4 cv = hb[(size_t)on * 256 + col4];
    cv.x *= vn; cv.y *= vn; cv.z *= vn; cv.w *= vn;
    ushort_t* row = Abig + (size_t)node * 4096;
    int f = col4 * 4;
    ushort4 mh, ml, ch, cl;
    split1(ax * inv, mh.x, ml.x); split1(ay * inv, mh.y, ml.y);
    split1(az * inv, mh.z, ml.z); split1(aw * inv, mh.w, ml.w);
    split1(cv.x, ch.x, cl.x); split1(cv.y, ch.y, cl.y);
    split1(cv.z, ch.z, cl.z); split1(cv.w, ch.w, cl.w);
    *(ushort4*)&row[f]        = mh;
    *(ushort4*)&row[1024 + f] = ml;
    *(ushort4*)&row[2048 + f] = ch;
    *(ushort4*)&row[3072 + f] = cl;
}

// ---------------- MFMA GEMM: 256x256 tile, 8 waves, cross-barrier operand preload ----------------
// Data layout/staging/read pattern = R3 (coalesced 64B gll sources, qsw-swizzled reads).
// Schedule (R5): one mid-chunk barrier; the NEXT chunk's hh-cluster operands (ah/bh) are read in
// THIS chunk's phase 2 from the other buffer (published by the mid-chunk barrier). Per chunk t:
//   phase1: issue al/bl reads (P) + DMA(t+1)->Q ; MFQ hh (operands preloaded -> starts with zero
//           post-barrier bubble) ; MFQ lh (al covered by hh's 1240cy)
//   VMW(0)  -- drains DMA(t+1), issued ~2500cy earlier
//   BARRIER -- publishes Q (chunk t+1 data); orders all P-reads before Q's next overwrite
//   phase2: issue ah/bh(t+1) reads from Q (covered by hl) ; MFQ hl
// This removes the chunk-boundary pattern [all waves finish MFMA -> read flood with idle MFMA
// pipe] that held R3 at 5850cy/chunk vs the 3725cy MFMA floor.
// MFMA order per acc element stays hh, lh, hl -> bitwise-identical C.

#define STR_(x) #x
#define VMW2_(n) asm volatile("s_waitcnt vmcnt(" STR_(n) ")" ::: "memory")
#define VMW(n) VMW2_(n)
#define BARM() do { __builtin_amdgcn_s_barrier(); asm volatile("" ::: "memory"); } while (0)

#define STG(Lw_, pl_, src_, c_) {                                                   \
    const ushort_t* s_ = (src_) + (c_);                                             \
    gll16(s_, (Lw_) + (pl_) * 8192);                                                \
    gll16(s_ + rstep, (Lw_) + (pl_) * 8192 + 4096);                                 \
}

#define MFQ(I0, Aarr, A0, Barr)                                                     \
    _Pragma("unroll")                                                               \
    for (int ii = 0; ii < 4; ++ii) {                                                \
        _Pragma("unroll")                                                           \
        for (int jj = 0; jj < 4; ++jj)                                              \
            acc[(I0) + ii][jj] = __builtin_amdgcn_mfma_f32_16x16x32_bf16(           \
                Aarr[(A0) + ii], Barr[jj], acc[(I0) + ii][jj], 0, 0, 0);            \
    }

// XA/XB: this chunk's preloaded ah/bh sets. YA/YB: next chunk's sets (filled in phase 2).
#define CHUNK(t_, b_, stg_, pre_, XA, XB, YA, YB) do {                              \
    int cs_ = ((t_) + 1 < NC2) ? ((t_) + 1) * 32 : 2 * KK + ((t_) + 1 - NC2) * 32;  \
    const ushort_t* Lr = L + (b_) * 32768;                                          \
    const ushort_t* Lq = L + (1 - (b_)) * 32768;                                    \
    ushort_t* Lw = L + (1 - (b_)) * 32768 + tid * 8;                                \
    bf16x8 al[8], bl[4];                                                            \
    _Pragma("unroll") for (int q = 0; q < 8; ++q)                                   \
        al[q] = *(const bf16x8*)&Lr[8192 + aoff + q * 512];                         \
    _Pragma("unroll") for (int q = 0; q < 4; ++q)                                   \
        bl[q] = *(const bf16x8*)&Lr[24576 + boff + q * 512];                        \
    if (stg_) {                                                                     \
        STG(Lw, 0, Ag, cs_);                                                        \
        STG(Lw, 2, Bg, cs_);                                                        \
        STG(Lw, 1, Ag + KK, cs_);                                                   \
        STG(Lw, 3, Bg + KK, cs_);                                                   \
    }                                                                               \
    __builtin_amdgcn_s_setprio(1);                                                  \
    MFQ(0, XA, 0, XB);                                                              \
    MFQ(4, XA, 4, XB);                                                              \
    MFQ(0, al, 0, XB);                                                              \
    MFQ(4, al, 4, XB);                                                              \
    __builtin_amdgcn_s_setprio(0);                                                  \
    VMW(0);                                                                         \
    BARM();                                                                         \
    if (pre_) {                                                                     \
        _Pragma("unroll") for (int q = 0; q < 8; ++q)                               \
            YA[q] = *(const bf16x8*)&Lq[aoff + q * 512];                            \
        _Pragma("unroll") for (int q = 0; q < 4; ++q)                               \
            YB[q] = *(const bf16x8*)&Lq[16384 + boff + q * 512];                    \
    }                                                                               \
    __builtin_amdgcn_s_setprio(1);                                                  \
    MFQ(0, XA, 0, bl);                                                              \
    MFQ(4, XA, 4, bl);                                                              \
    __builtin_amdgcn_s_setprio(0);                                                  \
} while (0)

template<int KK>
__global__ __launch_bounds__(512, 2) void gemm256(const ushort_t* __restrict__ Ab,
                                                  const ushort_t* __restrict__ Wb,
                                                  const float* __restrict__ bias,
                                                  float* __restrict__ C,
                                                  float* __restrict__ sp,
                                                  const float* __restrict__ pvec,
                                                  int npanels) {
    constexpr int LD  = 4 * KK;
    constexpr int NC  = KK / 16;     // 32-k chunks over [agg|cur]
    constexpr int NC2 = KK / 32;
    __shared__ ushort_t L[65536];    // 2 bufs x 4 planes x 8192 ushorts = 128 KiB

    int tid = threadIdx.x;
    int lane = tid & 63;
    int w = tid >> 6;
    int wm = w >> 2, wn = w & 3;     // 2x4 wave grid; wave tile 128x64

    // XCD-contiguous block mapping (nblocks divisible by 8: 256/208/176)
    int nb = npanels * 4;
    int per = nb >> 3;
    int bp = (blockIdx.x & 7) * per + (blockIdx.x >> 3);
    int panel = bp >> 2, cb = bp & 3;
    int m0 = panel * 256, n0 = cb * 256;

    // staging addressing (quad XOR swizzle, proven 2-way-free; 4 lanes cover 64B contiguous)
    int srow = tid >> 2;
    int gq = (tid & 3) ^ (srow & 3) ^ ((srow >> 2) & 3);
    const ushort_t* Ag = Ab + (size_t)(m0 + srow) * LD + gq * 8;
    const ushort_t* Bg = Wb + (size_t)(n0 + srow) * LD + gq * 8;
    const size_t rstep = (size_t)128 * LD;

    // fragment read offsets within a plane (ushort units): row*32 + quad*8
    int qsw = (lane >> 4) ^ (lane & 3) ^ ((lane >> 2) & 3);
    int aoff = (wm * 128 + (lane & 15)) * 32 + qsw * 8;
    int boff = (wn * 64 + (lane & 15)) * 32 + qsw * 8;

    f32x4 acc[8][4];
#pragma unroll
    for (int i = 0; i < 8; ++i)
#pragma unroll
        for (int j = 0; j < 4; ++j) acc[i][j] = (f32x4){0.f, 0.f, 0.f, 0.f};

    bf16x8 ahA[8], bhA[4], ahB[8], bhB[4];

    // prologue: stage chunk 0 into buf 0, publish, preload chunk-0 ah/bh into set A
    {
        ushort_t* Lw0 = L + tid * 8;
        STG(Lw0, 0, Ag, 0);
        STG(Lw0, 2, Bg, 0);
        STG(Lw0, 1, Ag + KK, 0);
        STG(Lw0, 3, Bg + KK, 0);
        VMW(0);
        BARM();
#pragma unroll
        for (int q = 0; q < 8; ++q) ahA[q] = *(const bf16x8*)&L[aoff + q * 512];
#pragma unroll
        for (int q = 0; q < 4; ++q) bhA[q] = *(const bf16x8*)&L[16384 + boff + q * 512];
    }

#pragma unroll 1
    for (int t = 0; t < NC - 2; t += 2) {
        CHUNK(t,     0, 1, 1, ahA, bhA, ahB, bhB);
        CHUNK(t + 1, 1, 1, 1, ahB, bhB, ahA, bhA);
    }
    CHUNK(NC - 2, 0, 1, 1, ahA, bhA, ahB, bhB);
    CHUNK(NC - 1, 1, 0, 0, ahB, bhB, ahA, bhA);   // last: no stage, no preload

    // ---- epilogue: bias + relu + C write + score partials ----
    float bj[4], pj[4];
#pragma unroll
    for (int j = 0; j < 4; ++j) {
        int col = n0 + wn * 64 + j * 16 + (lane & 15);
        bj[j] = bias[col];
        pj[j] = pvec[col];
    }
    int slot = cb * 4 + wn;
#pragma unroll
    for (int i = 0; i < 8; ++i) {
        int row0 = m0 + wm * 128 + i * 16 + (lane >> 4) * 4;
        float sacc[4] = {0.f, 0.f, 0.f, 0.f};
#pragma unroll
        for (int j = 0; j < 4; ++j) {
            int col = n0 + wn * 64 + j * 16 + (lane & 15);
#pragma unroll
            for (int r = 0; r < 4; ++r) {
                float v = acc[i][j][r] + bj[j];
                v = v > 0.f ? v : 0.f;
                C[(size_t)(row0 + r) * 1024 + col] = v;
                sacc[r] += v * pj[j];
            }
        }
#pragma unroll
        for (int r = 0; r < 4; ++r) {
            float sv_ = sacc[r];
            sv_ += __shfl_xor(sv_, 1);
            sv_ += __shfl_xor(sv_, 2);
            sv_ += __shfl_xor(sv_, 4);
            sv_ += __shfl_xor(sv_, 8);
            if ((lane & 15) == 0) sp[slot * SPROWS_ + row0 + r] = sv_;
        }
    }
}

// ---------------- tail: 9 blocks/graph (R8-proven, 1024 threads) ----------------
// roles 0-7: rank-select (redundant) + readout of a 32-float4-col slice.
// role 8:    rank-select + old_idx/vals write + edge remap + CSR rebuild.
// FIRST also selects '=' vs '+=' on the out write (removes d_out memset).

template<int FIRST>
__global__ __launch_bounds__(1024) void tail_kernel(const float* __restrict__ sp,
                                                    const float* __restrict__ pn,
                                                    const float* __restrict__ h,
                                                    float* __restrict__ out,
                                                    int n, int k,
                                                    int* __restrict__ old_idx, float* __restrict__ vals,
                                                    const int* __restrict__ ei,
                                                    int* __restrict__ esrc, int* __restrict__ edst,
                                                    int* __restrict__ emask,
                                                    int* __restrict__ counts, int* __restrict__ offsets,
                                                    int* __restrict__ adj, int do_edges) {
    __shared__ float sv[1024];
    __shared__ int   rmap[1024];
    __shared__ int   oi_s[1024];
    __shared__ float vv_s[1024];
    __shared__ float4 rmx[32][32];
    __shared__ float4 rsm[32][32];
    int b = blockIdx.x / 9, role = blockIdx.x % 9;
    int t = threadIdx.x;
    if (role == 8 && !do_edges) return;

    // phase 1: sum score partials, rank-select (stable descending top-k)
    float mine = -INFINITY;
    if (t < n) {
        int base = b * n + t;
        float s0 = 0.f;
#pragma unroll
        for (int c = 0; c < 16; ++c) s0 += sp[c * SPROWS_ + base];
        mine = s0;
    }
    sv[t] = mine;
    __syncthreads();
    int rank = 0;
#pragma unroll 4
    for (int j = 0; j < 1024; ++j) {
        float o = sv[j];
        rank += (o > mine) || (o == mine && j < t);
    }
    bool kept = (t < n) && (rank < k);
    rmap[t] = kept ? rank : -1;
    if (kept) {
        float tv = tanhf(mine / pn[0]);
        oi_s[rank] = b * n + t;
        vv_s[rank] = tv;
        if (role == 8) {
            old_idx[b * k + rank] = b * n + t;
            vals[b * k + rank] = tv;
        }
    }
    __syncthreads();

    if (role < 8) {
        // readout slice: 32 float4 cols, 32 row-groups
        int c32 = t & 31, g = t >> 5;
        int col4 = role * 32 + c32;
        const float4* hb = (const float4*)h;
        float4 mx = {-INFINITY, -INFINITY, -INFINITY, -INFINITY};
        float4 sm = {0.f, 0.f, 0.f, 0.f};
        for (int i = g; i < k; i += 32) {
            int o = oi_s[i];
            float wgt = vv_s[i];
            float4 v = hb[(size_t)o * 256 + col4];
            v.x *= wgt; v.y *= wgt; v.z *= wgt; v.w *= wgt;
            mx.x = fmaxf(mx.x, v.x); mx.y = fmaxf(mx.y, v.y);
            mx.z = fmaxf(mx.z, v.z); mx.w = fmaxf(mx.w, v.w);
            sm.x += v.x; sm.y += v.y; sm.z += v.z; sm.w += v.w;
        }
        rmx[g][c32] = mx; rsm[g][c32] = sm;
        __syncthreads();
        for (int s = 16; s > 0; s >>= 1) {
            if (g < s) {
                float4 om = rmx[g + s][c32], os = rsm[g + s][c32];
                float4 m = rmx[g][c32], ss2 = rsm[g][c32];
                m.x = fmaxf(m.x, om.x); m.y = fmaxf(m.y, om.y);
                m.z = fmaxf(m.z, om.z); m.w = fmaxf(m.w, om.w);
                ss2.x += os.x; ss2.y += os.y; ss2.z += os.z; ss2.w += os.w;
                rmx[g][c32] = m; rsm[g][c32] = ss2;
            }
            __syncthreads();
        }
        if (g == 0) {
            float4 m = rmx[0][c32], ss2 = rsm[0][c32];
            float invk = 1.0f / (float)k;
            float* o0 = out + (size_t)b * 2048 + col4 * 4;
            float* o1 = o0 + 1024;
            if (FIRST) {
                o0[0] = m.x; o0[1] = m.y; o0[2] = m.z; o0[3] = m.w;
                o1[0] = ss2.x * invk; o1[1] = ss2.y * invk;
                o1[2] = ss2.z * invk; o1[3] = ss2.w * invk;
            } else {
                o0[0] += m.x; o0[1] += m.y; o0[2] += m.z; o0[3] += m.w;
                o1[0] += ss2.x * invk; o1[1] += ss2.y * invk;
                o1[2] += ss2.z * invk; o1[3] += ss2.w * invk;
            }
        }
        return;
    }

    // role 8: edge phases
    __shared__ int cnt_s[1024];
    cnt_s[t] = 0;
    __syncthreads();
    int e0 = b * EPG_;
    // pass A: count new in-degrees
    for (int e = e0 + t; e < e0 + EPG_; e += 1024) {
        int ms = FIRST ? 1 : emask[e];
        if (ms) {
            int s = FIRST ? ei[e] : esrc[e];
            int dd = FIRST ? ei[E_ + e] : edst[e];
            int ns = rmap[s - b * n];
            int nd = rmap[dd - b * n];
            if (ns >= 0 && nd >= 0) atomicAdd(&cnt_s[nd], 1);
        }
    }
    __syncthreads();
    // scan over k
    int v = (t < k) ? cnt_s[t] : 0;
    oi_s[t] = v;
    __syncthreads();
    for (int off = 1; off < 1024; off <<= 1) {
        int tv = (t >= off) ? oi_s[t - off] : 0;
        __syncthreads();
        oi_s[t] += tv;
        __syncthreads();
    }
    int excl = oi_s[t] - v;
    if (t < k) {
        counts[b * k + t] = v;
        offsets[b * k + t] = e0 + excl;
        cnt_s[t] = excl;               // becomes fill cursor
    }
    __syncthreads();
    // pass B: remap + write final edges + fill adj
    for (int e = e0 + t; e < e0 + EPG_; e += 1024) {
        int ms = FIRST ? 1 : emask[e];
        if (ms) {
            int s = FIRST ? ei[e] : esrc[e];
            int dd = FIRST ? ei[E_ + e] : edst[e];
            int ns = rmap[s - b * n];
            int nd = rmap[dd - b * n];
            if (ns >= 0 && nd >= 0) {
                int gs = b * k + ns;
                esrc[e] = gs;
                edst[e] = b * k + nd;
                if (FIRST) emask[e] = 1;
                int pos = atomicAdd(&cnt_s[nd], 1);
                adj[e0 + pos] = gs;
            } else {
                emask[e] = 0;
            }
        } else if (FIRST) {
            emask[e] = 0;
        }
    }
}

// ---------------- host-side ----------------

extern "C" void kernel_launch(void* const* d_in, const int* in_sizes, int n_in,
                              void* d_out, int out_size, void* d_ws, size_t ws_size,
                              hipStream_t stream) {
    const float* x   = (const float*)d_in[0];
    const int*   ei  = (const int*)d_in[1];
    const float* W1l = (const float*)d_in[3];
    const float* b1  = (const float*)d_in[4];
    const float* W1r = (const float*)d_in[5];
    const float* p1  = (const float*)d_in[6];
    const float* W2l = (const float*)d_in[7];
    const float* b2  = (const float*)d_in[8];
    const float* W2r = (const float*)d_in[9];
    const float* p2  = (const float*)d_in[10];
    const float* W3l = (const float*)d_in[11];
    const float* b3  = (const float*)d_in[12];
    const float* W3r = (const float*)d_in[13];
    const float* p3  = (const float*)d_in[14];
    float* out = (float*)d_out;

    char* ws = (char*)d_ws;
    size_t off = 0;
    float* bufOut = (float*)(ws + off); off += (size_t)MP1_ * 1024 * 4;            // 64 MB
    ushort_t* Abig = (ushort_t*)(ws + off); off += (size_t)MP2_ * 4096 * 2;        // 109 MB
    ushort_t* Wb1 = (ushort_t*)(ws + off); off += (size_t)1024 * 2048 * 2;         // 4 MB
    ushort_t* Wb2 = (ushort_t*)(ws + off); off += (size_t)1024 * 4096 * 2;         // 8 MB
    ushort_t* Wb3 = (ushort_t*)(ws + off); off += (size_t)1024 * 4096 * 2;         // 8 MB
    float* sp = (float*)(ws + off); off += (size_t)16 * SPROWS_ * 4;               // 1 MB
    char* misc = ws + off;
    int*   counts = (int*)(misc + 0 * 65536);
    int*   offsets= (int*)(misc + 1 * 65536);
    int*   old_idx= (int*)(misc + 2 * 65536);
    float* vals   = (float*)(misc + 3 * 65536);
    float* pnormv = (float*)(misc + 4 * 65536);
    int*   adj    = (int*)(misc + 5 * 65536);
    int*   esrc   = (int*)(misc + 5 * 65536 + 1 * 1048576);
    int*   edst   = (int*)(misc + 5 * 65536 + 2 * 1048576);
    int*   emask  = (int*)(misc + 5 * 65536 + 3 * 1048576);

    // prep2: csr0 (16 blocks) + pnorms (3) + weight packing (2560)
    prep2_kernel<<<19 + (524288 + 2 * 1048576) / 1024, 1024, 0, stream>>>(
        ei, counts, offsets, adj, p1, p2, p3, pnormv,
        W1l, W1r, W2l, W2r, W3l, W3r, Wb1, Wb2, Wb3);

    // ---- layer 1 (K=512, n=1024 -> k=820) ----
    agg1_k512<<<16384, 128, 0, stream>>>(x, adj, offsets, counts, Abig);
    gemm256<512><<<(MP1_ / 256) * 4, 512, 0, stream>>>(Abig, Wb1, b1, bufOut, sp, p1, MP1_ / 256);
    tail_kernel<1><<<B_ * 9, 1024, 0, stream>>>(sp, pnormv + 0, bufOut, out, NP_, K1_,
                                                old_idx, vals, ei, esrc, edst, emask,
                                                counts, offsets, adj, 1);

    // ---- layer 2 (K=1024, n=820 -> k=656); pad rows zeroed by extra agg blocks ----
    agg23_k1024<2><<<32 * K1_ + (MP2_ - M2_), 128, 0, stream>>>(
        bufOut, adj, offsets, counts, old_idx, vals, Abig, K1_, M2_, MP2_ - M2_);
    gemm256<1024><<<(MP2_ / 256) * 4, 512, 0, stream>>>(Abig, Wb2, b2, bufOut, sp, p2, MP2_ / 256);
    tail_kernel<0><<<B_ * 9, 1024, 0, stream>>>(sp, pnormv + 1, bufOut, out, K1_, K2_,
                                                old_idx, vals, ei, esrc, edst, emask,
                                                counts, offsets, adj, 1);

    // ---- layer 3 (K=1024, n=656 -> k=525) ----
    agg23_k1024<3><<<32 * K2_ + (MP3_ - M3_), 128, 0, stream>>>(
        bufOut, adj, offsets, counts, old_idx, vals, Abig, K2_, M3_, MP3_ - M3_);
    gemm256<1024><<<(MP3_ / 256) * 4, 512, 0, stream>>>(Abig, Wb3, b3, bufOut, sp, p3, MP3_ / 256);
    tail_kernel<0><<<B_ * 9, 1024, 0, stream>>>(sp, pnormv + 2, bufOut, out, K2_, K3_,
                                                old_idx, vals, ei, esrc, edst, emask,
                                                counts, offsets, adj, 0);
}